// Round 1
// baseline (204.172 us; speedup 1.0000x reference)
//
#include <hip/hip_runtime.h>

#define VOCAB 32000
#define PDIM  128
#define BDIM  64
#define LDIM  4096

// ---------------------------------------------------------------------------
// Pass 1: transpose w_in (P=128, V=32000) -> w_t (V=32000, P=128).
// Each block handles a 64-column slab (all 128 rows). LDS tile padded to 65
// floats/row so both the coalesced load phase and the transposed store phase
// see only 2-way bank aliasing (free on gfx950 per m136).
// 500 blocks x 256 threads. Traffic: 16.4 MB read + 16.4 MB write.
// ---------------------------------------------------------------------------
__global__ __launch_bounds__(256) void wt_transpose_kernel(
    const float* __restrict__ w_in, float* __restrict__ w_t) {
    __shared__ float tile[128][65];
    const int v0 = blockIdx.x * 64;
    const int t  = threadIdx.x;

    // Load: 128 rows x 64 cols, coalesced along v.
    #pragma unroll
    for (int i = 0; i < (128 * 64) / 256; ++i) {
        int idx = i * 256 + t;
        int p = idx >> 6;
        int c = idx & 63;
        tile[p][c] = w_in[(size_t)p * VOCAB + v0 + c];
    }
    __syncthreads();

    // Store: 64 w_t rows of 128 contiguous floats (512B each), coalesced.
    #pragma unroll
    for (int i = 0; i < (64 * 128) / 256; ++i) {
        int idx = i * 256 + t;
        int r = idx >> 7;       // local v
        int p = idx & 127;
        w_t[(size_t)(v0 + r) * PDIM + p] = tile[p][r];
    }
}

// ---------------------------------------------------------------------------
// Pass 2: out[b,p,l] = w_t[x[b,l]][p].
// Thread handles 4 consecutive l and one 64-wide p-half:
//   - 4 idx loads, 4 row-half base pointers (contiguous 256B each)
//   - 16 iterations: 4x float4 gather (sequential within each row-half ->
//     every fetched line fully consumed), 4x4 register transpose,
//     4x float4 stores (lanes consecutive in l -> 1KB/wave contiguous).
// Grid: (B*L/4/256) l-blocks x 2 p-halves = 512 blocks x 256 threads.
// ---------------------------------------------------------------------------
__global__ __launch_bounds__(256) void encoder_gather_kernel(
    const int* __restrict__ x, const float* __restrict__ w_t,
    float* __restrict__ out) {
    const int half = blockIdx.x & 1;                       // p-half: 0 or 1
    const int g    = (blockIdx.x >> 1) * 256 + threadIdx.x; // l4-group id
    const int b    = g >> 10;                              // 1024 groups per b
    const int lg   = g & 1023;
    const int l    = lg << 2;

    const int xbase = b * LDIM + l;
    const int i0 = x[xbase + 0];
    const int i1 = x[xbase + 1];
    const int i2 = x[xbase + 2];
    const int i3 = x[xbase + 3];

    const int poff = half * 64;
    const float4* r0 = (const float4*)(w_t + (size_t)i0 * PDIM + poff);
    const float4* r1 = (const float4*)(w_t + (size_t)i1 * PDIM + poff);
    const float4* r2 = (const float4*)(w_t + (size_t)i2 * PDIM + poff);
    const float4* r3 = (const float4*)(w_t + (size_t)i3 * PDIM + poff);

    float* ob = out + ((size_t)(b * PDIM + poff)) * LDIM + l;

    #pragma unroll 4
    for (int i = 0; i < 16; ++i) {
        float4 a0 = r0[i];
        float4 a1 = r1[i];
        float4 a2 = r2[i];
        float4 a3 = r3[i];
        float4 s0 = make_float4(a0.x, a1.x, a2.x, a3.x);
        float4 s1 = make_float4(a0.y, a1.y, a2.y, a3.y);
        float4 s2 = make_float4(a0.z, a1.z, a2.z, a3.z);
        float4 s3 = make_float4(a0.w, a1.w, a2.w, a3.w);
        float* op = ob + (size_t)(i * 4) * LDIM;
        *(float4*)(op)            = s0;
        *(float4*)(op + LDIM)     = s1;
        *(float4*)(op + 2 * LDIM) = s2;
        *(float4*)(op + 3 * LDIM) = s3;
    }
}

// ---------------------------------------------------------------------------
// Fallback (only if d_ws can't hold the 16.4MB transposed table): direct
// strided gather from w_in. Correct but slower (random 4B reads).
// ---------------------------------------------------------------------------
__global__ __launch_bounds__(256) void encoder_direct_kernel(
    const int* __restrict__ x, const float* __restrict__ w_in,
    float* __restrict__ out) {
    const int g = blockIdx.x * 256 + threadIdx.x;  // one per (b,l)
    const int b = g >> 12;                         // L = 4096
    const int l = g & 4095;
    const int idx = x[b * LDIM + l];
    const float* src = w_in + idx;
    float* dst = out + (size_t)b * PDIM * LDIM + l;
    #pragma unroll 4
    for (int p = 0; p < PDIM; ++p) {
        dst[(size_t)p * LDIM] = src[(size_t)p * VOCAB];
    }
}

extern "C" void kernel_launch(void* const* d_in, const int* in_sizes, int n_in,
                              void* d_out, int out_size, void* d_ws, size_t ws_size,
                              hipStream_t stream) {
    const int*   x    = (const int*)d_in[0];
    const float* w_in = (const float*)d_in[1];
    float*       out  = (float*)d_out;

    const size_t wt_bytes = (size_t)VOCAB * PDIM * sizeof(float);
    if (ws_size >= wt_bytes) {
        float* w_t = (float*)d_ws;
        wt_transpose_kernel<<<VOCAB / 64, 256, 0, stream>>>(w_in, w_t);
        encoder_gather_kernel<<<((BDIM * LDIM) / 4 / 256) * 2, 256, 0, stream>>>(
            x, w_t, out);
    } else {
        encoder_direct_kernel<<<(BDIM * LDIM) / 256, 256, 0, stream>>>(x, w_in, out);
    }
}

// Round 3
// 167.644 us; speedup vs baseline: 1.2179x; 1.2179x over previous
//
#include <hip/hip_runtime.h>

#define VOCAB 32000
#define PDIM  128
#define BDIM  64
#define LDIM  4096

typedef float vfloat4 __attribute__((ext_vector_type(4)));

// ---------------------------------------------------------------------------
// Pass 1: transpose w_in (P=128, V=32000) -> w_t (V=32000, P=128).
// Each block handles a 64-column slab (all 128 rows). LDS tile padded to 65
// floats/row. 500 blocks x 256 threads. Traffic: 16.4 MB read + 16.4 MB write.
// ---------------------------------------------------------------------------
__global__ __launch_bounds__(256) void wt_transpose_kernel(
    const float* __restrict__ w_in, float* __restrict__ w_t) {
    __shared__ float tile[128][65];
    const int v0 = blockIdx.x * 64;
    const int t  = threadIdx.x;

    #pragma unroll
    for (int i = 0; i < (128 * 64) / 256; ++i) {
        int idx = i * 256 + t;
        int p = idx >> 6;
        int c = idx & 63;
        tile[p][c] = w_in[(size_t)p * VOCAB + v0 + c];
    }
    __syncthreads();

    #pragma unroll
    for (int i = 0; i < (64 * 128) / 256; ++i) {
        int idx = i * 256 + t;
        int r = idx >> 7;       // local v
        int p = idx & 127;
        w_t[(size_t)(v0 + r) * PDIM + p] = tile[p][r];
    }
}

// ---------------------------------------------------------------------------
// Pass 2: block = 64 tokens x full P=128.
//  Phase 1: cooperative coalesced load of the 64 gathered w_t rows into LDS.
//    Half-wave (32 lanes) per row -> each instruction touches 2 contiguous
//    512 B segments (8 lines, fully consumed) instead of 64 random lines.
//  Phase 2: transpose out of LDS; lanes consecutive in l write float4 ->
//    1 KB contiguous per wave instruction, non-temporal (out has zero reuse;
//    keep L2 for w_t).
//  LDS tile padded to 129 floats/row: phase-2 reads tile[j][p] are 2-way per
//  bank (free per m136), phase-1 row writes sequential (conflict-free).
// Grid: 4096 blocks x 256 threads.
// ---------------------------------------------------------------------------
__global__ __launch_bounds__(256) void encoder_gather_kernel(
    const int* __restrict__ x, const float* __restrict__ w_t,
    float* __restrict__ out) {
    __shared__ float tile[64][129];
    __shared__ int   sidx[64];

    const int t  = threadIdx.x;
    const int g  = blockIdx.x;       // 4096 blocks: 64 l-tiles x 64 b
    const int b  = g >> 6;
    const int l0 = (g & 63) << 6;

    if (t < 64) sidx[t] = x[b * LDIM + l0 + t];
    __syncthreads();

    // Phase 1: 8 passes x 8 rows; half-wave per row, float4 per lane.
    #pragma unroll
    for (int pass = 0; pass < 8; ++pass) {
        int r = pass * 8 + (t >> 5);
        int c = (t & 31) * 4;
        float4 v = *(const float4*)(w_t + (size_t)sidx[r] * PDIM + c);
        *(float4*)&tile[r][c] = v;
    }
    __syncthreads();

    // Phase 2: 8 passes; p = pass*16 + (t>>4), j = (t&15)*4.
    const int j     = (t & 15) * 4;
    const int pbase = t >> 4;
    float* ob = out + (size_t)b * PDIM * LDIM + l0 + j;
    #pragma unroll
    for (int pass = 0; pass < 8; ++pass) {
        int p = pass * 16 + pbase;
        vfloat4 s;
        s.x = tile[j + 0][p];
        s.y = tile[j + 1][p];
        s.z = tile[j + 2][p];
        s.w = tile[j + 3][p];
        __builtin_nontemporal_store(s, (vfloat4*)(ob + (size_t)p * LDIM));
    }
}

// ---------------------------------------------------------------------------
// Fallback (only if d_ws can't hold the 16.4MB transposed table).
// ---------------------------------------------------------------------------
__global__ __launch_bounds__(256) void encoder_direct_kernel(
    const int* __restrict__ x, const float* __restrict__ w_in,
    float* __restrict__ out) {
    const int g = blockIdx.x * 256 + threadIdx.x;
    const int b = g >> 12;
    const int l = g & 4095;
    const int idx = x[b * LDIM + l];
    const float* src = w_in + idx;
    float* dst = out + (size_t)b * PDIM * LDIM + l;
    #pragma unroll 4
    for (int p = 0; p < PDIM; ++p) {
        dst[(size_t)p * LDIM] = src[(size_t)p * VOCAB];
    }
}

extern "C" void kernel_launch(void* const* d_in, const int* in_sizes, int n_in,
                              void* d_out, int out_size, void* d_ws, size_t ws_size,
                              hipStream_t stream) {
    const int*   x    = (const int*)d_in[0];
    const float* w_in = (const float*)d_in[1];
    float*       out  = (float*)d_out;

    const size_t wt_bytes = (size_t)VOCAB * PDIM * sizeof(float);
    if (ws_size >= wt_bytes) {
        float* w_t = (float*)d_ws;
        wt_transpose_kernel<<<VOCAB / 64, 256, 0, stream>>>(w_in, w_t);
        encoder_gather_kernel<<<(BDIM * LDIM) / 64, 256, 0, stream>>>(x, w_t, out);
    } else {
        encoder_direct_kernel<<<(BDIM * LDIM) / 256, 256, 0, stream>>>(x, w_in, out);
    }
}